// Round 1
// baseline (588.019 us; speedup 1.0000x reference)
//
#include <hip/hip_runtime.h>
#include <hip/hip_bf16.h>

#define NR 8192
#define DIN 200
#define DOUT 128

typedef __attribute__((ext_vector_type(8))) short short8;
typedef __attribute__((ext_vector_type(4))) float f32x4;

__device__ __forceinline__ unsigned short f2bf(float x) {
    union { float f; unsigned u; } v; v.f = x;
    unsigned r = v.u + 0x7FFFu + ((v.u >> 16) & 1u);  // RNE
    return (unsigned short)(r >> 16);
}

__device__ __forceinline__ float4 sig4(float4 x) {
    float4 s;
    s.x = fmaxf(__builtin_amdgcn_rcpf(1.f + __expf(-x.x)), 0.1f);
    s.y = fmaxf(__builtin_amdgcn_rcpf(1.f + __expf(-x.y)), 0.1f);
    s.z = fmaxf(__builtin_amdgcn_rcpf(1.f + __expf(-x.z)), 0.1f);
    s.w = fmaxf(__builtin_amdgcn_rcpf(1.f + __expf(-x.w)), 0.1f);
    return s;
}

// ---------------- K1: dis = rsqrt(rowsum(max(sigmoid(A),0.1))) -- READ-ONLY ----------------
__global__ __launch_bounds__(256) void k_sum(const float* __restrict__ A,
                                             float* __restrict__ dis) {
    const int row = blockIdx.x;
    const float4* __restrict__ ar = (const float4*)(A + (size_t)row * NR);
    float sum = 0.f;
#pragma unroll
    for (int i = 0; i < 8; ++i) {
        float4 s = sig4(ar[i * 256 + threadIdx.x]);
        sum += (s.x + s.y) + (s.z + s.w);
    }
#pragma unroll
    for (int off = 32; off > 0; off >>= 1) sum += __shfl_down(sum, off, 64);
    __shared__ float red[4];
    if ((threadIdx.x & 63) == 0) red[threadIdx.x >> 6] = sum;
    __syncthreads();
    if (threadIdx.x == 0)
        dis[row] = __builtin_amdgcn_rsqf((red[0] + red[1]) + (red[2] + red[3]));
}

// ---------------- K2: VT[c][j] = bf16( dis[j] * (H[j,:]@W[:,c] + b[c]) ), K-major ----------------
__global__ __launch_bounds__(256) void k_vt(const float* __restrict__ H,
                                            const float* __restrict__ W,
                                            const float* __restrict__ bias,
                                            const float* __restrict__ dis,
                                            unsigned short* __restrict__ VT) {
    __shared__ float hs[32 * 201];  // +1 pad breaks 8-way bank conflict across rgrps
    const int rowBase = blockIdx.x * 32;
    for (int i = threadIdx.x; i < 32 * DIN; i += 256) {
        int r = i / DIN;
        int k = i - r * DIN;
        hs[r * 201 + k] = H[(size_t)rowBase * DIN + i];
    }
    __syncthreads();
    const int c0 = (threadIdx.x & 31) * 4;  // 4 cols
    const int rg = threadIdx.x >> 5;        // 8 row-groups x 4 rows
    float acc[4][4];
#pragma unroll
    for (int r = 0; r < 4; ++r)
#pragma unroll
        for (int i = 0; i < 4; ++i) acc[r][i] = 0.f;
#pragma unroll 4
    for (int k = 0; k < DIN; ++k) {
        float4 w4 = *(const float4*)(W + k * DOUT + c0);
#pragma unroll
        for (int r = 0; r < 4; ++r) {
            float h = hs[(rg * 4 + r) * 201 + k];
            acc[r][0] = fmaf(h, w4.x, acc[r][0]);
            acc[r][1] = fmaf(h, w4.y, acc[r][1]);
            acc[r][2] = fmaf(h, w4.z, acc[r][2]);
            acc[r][3] = fmaf(h, w4.w, acc[r][3]);
        }
    }
    float4 b4 = *(const float4*)(bias + c0);
    float bb[4] = {b4.x, b4.y, b4.z, b4.w};
    float dsc[4];
#pragma unroll
    for (int r = 0; r < 4; ++r) dsc[r] = dis[rowBase + rg * 4 + r];
#pragma unroll
    for (int i = 0; i < 4; ++i) {
        ushort4 pk;
        pk.x = f2bf(dsc[0] * (acc[0][i] + bb[i]));
        pk.y = f2bf(dsc[1] * (acc[1][i] + bb[i]));
        pk.z = f2bf(dsc[2] * (acc[2][i] + bb[i]));
        pk.w = f2bf(dsc[3] * (acc[3][i] + bb[i]));
        *(ushort4*)(VT + (size_t)(c0 + i) * NR + rowBase + rg * 4) = pk;
    }
}

// ---------------- K3: fused sigmoid + A2-write + P[s] = A2[:, ks] @ V[ks, :] ----------------
#define BK 32
#define LDK 40   // padded K-stride in elems (80 B -> 2-way bank aliasing only, free)
#define NIT 128  // 4096 / BK

__global__ __launch_bounds__(256) void k_gemm(const float* __restrict__ A,
                                              const unsigned short* __restrict__ VT,
                                              float* __restrict__ A2,
                                              float* __restrict__ P) {
    __shared__ alignas(16) unsigned short lA[2][32 * LDK];
    __shared__ alignas(16) unsigned short lV[2][128 * LDK];
    const int tid = threadIdx.x;
    const int blockRow = blockIdx.x & 255;
    const int s = blockIdx.x >> 8;  // K-split half
    const int rowBase = blockRow * 32;
    const size_t kb0 = (size_t)s * 4096;

    // A staging: 32 rows x 32 k per iter; thread -> (row am, 4 consecutive k)
    const int am = tid >> 3, ak = (tid & 7) * 4;
    const size_t aoff = (size_t)(rowBase + am) * NR + kb0 + ak;
    const float* __restrict__ ap = A + aoff;
    float* __restrict__ a2p = A2 + aoff;
    // V staging: 128 cols x 32 k; thread -> (col vc & vc+64, 8 consecutive k)
    const int vc = tid >> 2, vq = (tid & 3) * 8;
    const unsigned short* __restrict__ vp0 = VT + (size_t)vc * NR + kb0 + vq;
    const unsigned short* __restrict__ vp1 = vp0 + (size_t)64 * NR;

    const int lane = tid & 63, w = tid >> 6;
    const int rt = w & 1, cg = w >> 1;  // wave: 16 rows x 64 cols
    const int fm = lane & 15, kq = lane >> 4;

    f32x4 acc[4];
#pragma unroll
    for (int nt = 0; nt < 4; ++nt) {
        acc[nt][0] = 0.f; acc[nt][1] = 0.f; acc[nt][2] = 0.f; acc[nt][3] = 0.f;
    }

    float4 ga, gv0, gv1;

    // prologue: load iter 0, sigmoid + A2-store + stage buf 0, load iter 1
    ga  = *(const float4*)(ap);
    gv0 = *(const float4*)(vp0);
    gv1 = *(const float4*)(vp1);
    {
        float4 sg = sig4(ga);
        *(float4*)(a2p) = sg;
        ushort4 pa; pa.x = f2bf(sg.x); pa.y = f2bf(sg.y); pa.z = f2bf(sg.z); pa.w = f2bf(sg.w);
        *(ushort4*)(&lA[0][am * LDK + ak]) = pa;
        *(float4*)(&lV[0][vc * LDK + vq]) = gv0;
        *(float4*)(&lV[0][(vc + 64) * LDK + vq]) = gv1;
    }
    ga  = *(const float4*)(ap + BK);
    gv0 = *(const float4*)(vp0 + BK);
    gv1 = *(const float4*)(vp1 + BK);

    const unsigned short* lap = &lA[0][(rt * 16 + fm) * LDK + kq * 8];
    const unsigned short* lvp = &lV[0][(cg * 64 + fm) * LDK + kq * 8];
    const int strideA = 32 * LDK;
    const int strideV = 128 * LDK;

    for (int i = 0; i < NIT; ++i) {
        __syncthreads();
        if (i + 1 < NIT) {  // sigmoid + A2-store + stage next buffer
            const int nb = (i + 1) & 1;
            float4 sg = sig4(ga);
            *(float4*)(a2p + (size_t)(i + 1) * BK) = sg;
            ushort4 pa; pa.x = f2bf(sg.x); pa.y = f2bf(sg.y); pa.z = f2bf(sg.z); pa.w = f2bf(sg.w);
            *(ushort4*)(&lA[nb][am * LDK + ak]) = pa;
            *(float4*)(&lV[nb][vc * LDK + vq]) = gv0;
            *(float4*)(&lV[nb][(vc + 64) * LDK + vq]) = gv1;
        }
        if (i + 2 < NIT) {  // fire loads 2 iters ahead
            const size_t off = (size_t)(i + 2) * BK;
            ga  = *(const float4*)(ap + off);
            gv0 = *(const float4*)(vp0 + off);
            gv1 = *(const float4*)(vp1 + off);
        }
        const int cb = i & 1;
        short8 a8 = *(const short8*)(lap + cb * strideA);
#pragma unroll
        for (int nt = 0; nt < 4; ++nt) {
            short8 b8 = *(const short8*)(lvp + cb * strideV + nt * 16 * LDK);
            acc[nt] = __builtin_amdgcn_mfma_f32_16x16x32_bf16(a8, b8, acc[nt], 0, 0, 0);
        }
    }

    // epilogue: raw f32 partials (C/D layout: col=lane&15, row=(lane>>4)*4+reg)
    float* __restrict__ Pp = P + (size_t)s * ((size_t)NR * DOUT);
    const int row0 = rowBase + rt * 16 + kq * 4;
    const int col0 = cg * 64 + fm;
#pragma unroll
    for (int nt = 0; nt < 4; ++nt) {
#pragma unroll
        for (int v = 0; v < 4; ++v) {
            Pp[(size_t)(row0 + v) * DOUT + col0 + nt * 16] = acc[nt][v];
        }
    }
}

// ---------------- K4: out = leaky( dis[i] * (P0 + P1) ) ----------------
__global__ __launch_bounds__(256) void k_comb(const float* __restrict__ P,
                                              const float* __restrict__ dis,
                                              float* __restrict__ out) {
    const int idx = blockIdx.x * 256 + threadIdx.x;  // float4 index, 262144 total
    const float d = dis[idx >> 5];
    const float4 p0 = *(const float4*)(P + (size_t)idx * 4);
    const float4 p1 = *(const float4*)(P + (size_t)idx * 4 + (size_t)NR * DOUT);
    float4 o;
    o.x = d * (p0.x + p1.x); o.x = o.x >= 0.f ? o.x : 0.01f * o.x;
    o.y = d * (p0.y + p1.y); o.y = o.y >= 0.f ? o.y : 0.01f * o.y;
    o.z = d * (p0.z + p1.z); o.z = o.z >= 0.f ? o.z : 0.01f * o.z;
    o.w = d * (p0.w + p1.w); o.w = o.w >= 0.f ? o.w : 0.01f * o.w;
    *(float4*)(out + (size_t)idx * 4) = o;
}

extern "C" void kernel_launch(void* const* d_in, const int* in_sizes, int n_in,
                              void* d_out, int out_size, void* d_ws, size_t ws_size,
                              hipStream_t stream) {
    const float* H = (const float*)d_in[0];
    const float* A = (const float*)d_in[1];
    const float* W = (const float*)d_in[2];
    const float* b = (const float*)d_in[3];

    float* out = (float*)d_out;                       // [8192,128]
    float* A2  = out + (size_t)NR * DOUT;             // [8192,8192] (second output)

    char* ws = (char*)d_ws;
    float* dis = (float*)ws;                                  // 32 KB
    unsigned short* VT = (unsigned short*)(ws + 65536);       // 2 MB (bf16, [128][8192])
    float* P = (float*)(ws + (4u << 20));                     // 8 MB (f32, [2][8192][128])

    k_sum <<<NR,   256, 0, stream>>>(A, dis);
    k_vt  <<<256,  256, 0, stream>>>(H, W, b, dis, VT);
    k_gemm<<<512,  256, 0, stream>>>(A, VT, A2, P);
    k_comb<<<1024, 256, 0, stream>>>(P, dis, out);
}

// Round 2
// 527.265 us; speedup vs baseline: 1.1152x; 1.1152x over previous
//
#include <hip/hip_runtime.h>
#include <hip/hip_bf16.h>

#define NR 8192
#define DIN 200
#define DOUT 128

#define NSPLIT 4
#define KSPL 2048   // NR / NSPLIT
#define BK 32
#define LDK 40      // padded K-stride in elems (80 B -> 2-way bank aliasing only, free)
#define NIT 64      // KSPL / BK

typedef __attribute__((ext_vector_type(8))) short short8;
typedef __attribute__((ext_vector_type(4))) float f32x4;
typedef __attribute__((ext_vector_type(4))) float fv4;
typedef __attribute__((ext_vector_type(4))) unsigned short u16x4;

__device__ __forceinline__ unsigned short f2bf(float x) {
    union { float f; unsigned u; } v; v.f = x;
    unsigned r = v.u + 0x7FFFu + ((v.u >> 16) & 1u);  // RNE
    return (unsigned short)(r >> 16);
}

__device__ __forceinline__ fv4 sig4(fv4 x) {
    fv4 s;
    s[0] = fmaxf(__builtin_amdgcn_rcpf(1.f + __expf(-x[0])), 0.1f);
    s[1] = fmaxf(__builtin_amdgcn_rcpf(1.f + __expf(-x[1])), 0.1f);
    s[2] = fmaxf(__builtin_amdgcn_rcpf(1.f + __expf(-x[2])), 0.1f);
    s[3] = fmaxf(__builtin_amdgcn_rcpf(1.f + __expf(-x[3])), 0.1f);
    return s;
}

// ---- K1: single pass over A: dis = rsqrt(rowsum(sig)), A2 = f32 sig (NT), SA = bf16 sig ----
__global__ __launch_bounds__(256) void k_sum(const float* __restrict__ A,
                                             float* __restrict__ A2,
                                             unsigned short* __restrict__ SA,
                                             float* __restrict__ dis) {
    const int row = blockIdx.x;
    const fv4* __restrict__ ar = (const fv4*)(A + (size_t)row * NR);
    fv4* __restrict__ a2r = (fv4*)(A2 + (size_t)row * NR);
    u16x4* __restrict__ sar = (u16x4*)(SA + (size_t)row * NR);
    float sum = 0.f;
#pragma unroll
    for (int i = 0; i < 8; ++i) {
        const int idx = i * 256 + threadIdx.x;
        fv4 x = __builtin_nontemporal_load(&ar[idx]);   // A never re-read: keep out of L3
        fv4 s = sig4(x);
        __builtin_nontemporal_store(s, &a2r[idx]);      // A2 never re-read: keep out of L3
        u16x4 pk;
        pk[0] = f2bf(s[0]); pk[1] = f2bf(s[1]); pk[2] = f2bf(s[2]); pk[3] = f2bf(s[3]);
        sar[idx] = pk;                                  // SA re-read by k_gemm: cacheable
        sum += (s[0] + s[1]) + (s[2] + s[3]);
    }
#pragma unroll
    for (int off = 32; off > 0; off >>= 1) sum += __shfl_down(sum, off, 64);
    __shared__ float red[4];
    if ((threadIdx.x & 63) == 0) red[threadIdx.x >> 6] = sum;
    __syncthreads();
    if (threadIdx.x == 0)
        dis[row] = __builtin_amdgcn_rsqf((red[0] + red[1]) + (red[2] + red[3]));
}

// ---------------- K2: VT[c][j] = bf16( dis[j] * (H[j,:]@W[:,c] + b[c]) ), K-major ----------------
__global__ __launch_bounds__(256) void k_vt(const float* __restrict__ H,
                                            const float* __restrict__ W,
                                            const float* __restrict__ bias,
                                            const float* __restrict__ dis,
                                            unsigned short* __restrict__ VT) {
    __shared__ float hs[32 * 201];  // +1 pad breaks 8-way bank conflict across rgrps
    const int rowBase = blockIdx.x * 32;
    for (int i = threadIdx.x; i < 32 * DIN; i += 256) {
        int r = i / DIN;
        int k = i - r * DIN;
        hs[r * 201 + k] = H[(size_t)rowBase * DIN + i];
    }
    __syncthreads();
    const int c0 = (threadIdx.x & 31) * 4;  // 4 cols
    const int rg = threadIdx.x >> 5;        // 8 row-groups x 4 rows
    float acc[4][4];
#pragma unroll
    for (int r = 0; r < 4; ++r)
#pragma unroll
        for (int i = 0; i < 4; ++i) acc[r][i] = 0.f;
#pragma unroll 4
    for (int k = 0; k < DIN; ++k) {
        float4 w4 = *(const float4*)(W + k * DOUT + c0);
#pragma unroll
        for (int r = 0; r < 4; ++r) {
            float h = hs[(rg * 4 + r) * 201 + k];
            acc[r][0] = fmaf(h, w4.x, acc[r][0]);
            acc[r][1] = fmaf(h, w4.y, acc[r][1]);
            acc[r][2] = fmaf(h, w4.z, acc[r][2]);
            acc[r][3] = fmaf(h, w4.w, acc[r][3]);
        }
    }
    float4 b4 = *(const float4*)(bias + c0);
    float bb[4] = {b4.x, b4.y, b4.z, b4.w};
    float dsc[4];
#pragma unroll
    for (int r = 0; r < 4; ++r) dsc[r] = dis[rowBase + rg * 4 + r];
#pragma unroll
    for (int i = 0; i < 4; ++i) {
        ushort4 pk;
        pk.x = f2bf(dsc[0] * (acc[0][i] + bb[i]));
        pk.y = f2bf(dsc[1] * (acc[1][i] + bb[i]));
        pk.z = f2bf(dsc[2] * (acc[2][i] + bb[i]));
        pk.w = f2bf(dsc[3] * (acc[3][i] + bb[i]));
        *(ushort4*)(VT + (size_t)(c0 + i) * NR + rowBase + rg * 4) = pk;
    }
}

// ---------------- K3: P[s] = SA[:, ks] @ V[ks, :]  (bf16 MFMA, f32 partials) ----------------
__global__ __launch_bounds__(256, 4) void k_gemm(const unsigned short* __restrict__ SA,
                                                 const unsigned short* __restrict__ VT,
                                                 float* __restrict__ P) {
    __shared__ alignas(16) unsigned short lA[2][32 * LDK];
    __shared__ alignas(16) unsigned short lV[2][128 * LDK];
    const int tid = threadIdx.x;
    const int blockRow = blockIdx.x & 255;
    const int s = blockIdx.x >> 8;  // K-split quarter
    const int rowBase = blockRow * 32;
    const size_t kb0 = (size_t)s * KSPL;

    // A staging: 32 rows x 32 k per iter; thread -> (row am, 4 consecutive k), 8B loads
    const int am = tid >> 3, ak = (tid & 7) * 4;
    const unsigned short* __restrict__ ap = SA + (size_t)(rowBase + am) * NR + kb0 + ak;
    // V staging: 128 cols x 32 k; thread -> (col vc & vc+64, 8 consecutive k)
    const int vc = tid >> 2, vq = (tid & 3) * 8;
    const unsigned short* __restrict__ vp0 = VT + (size_t)vc * NR + kb0 + vq;
    const unsigned short* __restrict__ vp1 = vp0 + (size_t)64 * NR;

    const int lane = tid & 63, w = tid >> 6;
    const int rt = w & 1, cg = w >> 1;  // wave: 16 rows x 64 cols
    const int fm = lane & 15, kq = lane >> 4;

    f32x4 acc[4];
#pragma unroll
    for (int nt = 0; nt < 4; ++nt) {
        acc[nt][0] = 0.f; acc[nt][1] = 0.f; acc[nt][2] = 0.f; acc[nt][3] = 0.f;
    }

    u16x4 ga; short8 gv0, gv1;

    // prologue: load iter 0, stage buf 0, load iter 1
    ga  = *(const u16x4*)(ap);
    gv0 = *(const short8*)(vp0);
    gv1 = *(const short8*)(vp1);
    *(u16x4*)(&lA[0][am * LDK + ak]) = ga;
    *(short8*)(&lV[0][vc * LDK + vq]) = gv0;
    *(short8*)(&lV[0][(vc + 64) * LDK + vq]) = gv1;
    ga  = *(const u16x4*)(ap + BK);
    gv0 = *(const short8*)(vp0 + BK);
    gv1 = *(const short8*)(vp1 + BK);

    const unsigned short* lap = &lA[0][(rt * 16 + fm) * LDK + kq * 8];
    const unsigned short* lvp = &lV[0][(cg * 64 + fm) * LDK + kq * 8];
    const int strideA = 32 * LDK;
    const int strideV = 128 * LDK;

    for (int i = 0; i < NIT; ++i) {
        __syncthreads();
        if (i + 1 < NIT) {  // stage next buffer (pure moves, no conversion)
            const int nb = (i + 1) & 1;
            *(u16x4*)(&lA[nb][am * LDK + ak]) = ga;
            *(short8*)(&lV[nb][vc * LDK + vq]) = gv0;
            *(short8*)(&lV[nb][(vc + 64) * LDK + vq]) = gv1;
        }
        if (i + 2 < NIT) {  // fire loads 2 iters ahead
            const size_t off = (size_t)(i + 2) * BK;
            ga  = *(const u16x4*)(ap + off);
            gv0 = *(const short8*)(vp0 + off);
            gv1 = *(const short8*)(vp1 + off);
        }
        const int cb = i & 1;
        short8 a8 = *(const short8*)(lap + cb * strideA);
#pragma unroll
        for (int nt = 0; nt < 4; ++nt) {
            short8 b8 = *(const short8*)(lvp + cb * strideV + nt * 16 * LDK);
            acc[nt] = __builtin_amdgcn_mfma_f32_16x16x32_bf16(a8, b8, acc[nt], 0, 0, 0);
        }
    }

    // epilogue: raw f32 partials (C/D layout: col=lane&15, row=(lane>>4)*4+reg)
    float* __restrict__ Pp = P + (size_t)s * ((size_t)NR * DOUT);
    const int row0 = rowBase + rt * 16 + kq * 4;
    const int col0 = cg * 64 + fm;
#pragma unroll
    for (int nt = 0; nt < 4; ++nt) {
#pragma unroll
        for (int v = 0; v < 4; ++v) {
            Pp[(size_t)(row0 + v) * DOUT + col0 + nt * 16] = acc[nt][v];
        }
    }
}

// ---------------- K4: out = leaky( dis[i] * (P0 + P1 + P2 + P3) ) ----------------
__global__ __launch_bounds__(256) void k_comb(const float* __restrict__ P,
                                              const float* __restrict__ dis,
                                              float* __restrict__ out) {
    const int idx = blockIdx.x * 256 + threadIdx.x;  // float4 index, 262144 total
    const float d = dis[idx >> 5];
    const size_t sl = (size_t)NR * DOUT;
    const fv4 p0 = *(const fv4*)(P + (size_t)idx * 4);
    const fv4 p1 = *(const fv4*)(P + (size_t)idx * 4 + sl);
    const fv4 p2 = *(const fv4*)(P + (size_t)idx * 4 + 2 * sl);
    const fv4 p3 = *(const fv4*)(P + (size_t)idx * 4 + 3 * sl);
    fv4 t = (p0 + p1) + (p2 + p3);
    fv4 o;
#pragma unroll
    for (int j = 0; j < 4; ++j) {
        float v = d * t[j];
        o[j] = v >= 0.f ? v : 0.01f * v;
    }
    *(fv4*)(out + (size_t)idx * 4) = o;
}

extern "C" void kernel_launch(void* const* d_in, const int* in_sizes, int n_in,
                              void* d_out, int out_size, void* d_ws, size_t ws_size,
                              hipStream_t stream) {
    const float* H = (const float*)d_in[0];
    const float* A = (const float*)d_in[1];
    const float* W = (const float*)d_in[2];
    const float* b = (const float*)d_in[3];

    float* out = (float*)d_out;                       // [8192,128]
    float* A2  = out + (size_t)NR * DOUT;             // [8192,8192] (second output)

    char* ws = (char*)d_ws;
    float* dis = (float*)ws;                                    // 32 KB @ 0
    unsigned short* VT = (unsigned short*)(ws + 65536);         // 2 MB   @ 64 KB
    float* P = (float*)(ws + (4ull << 20));                     // 16 MB  @ 4 MB (4 splits x 4 MB)
    unsigned short* SA = (unsigned short*)(ws + (20ull << 20)); // 128 MB @ 20 MB (bf16 A2)

    k_sum <<<NR,   256, 0, stream>>>(A, A2, SA, dis);
    k_vt  <<<256,  256, 0, stream>>>(H, W, b, dis, VT);
    k_gemm<<<1024, 256, 0, stream>>>(SA, VT, P);
    k_comb<<<1024, 256, 0, stream>>>(P, dis, out);
}